// Round 8
// baseline (10285.260 us; speedup 1.0000x reference)
//
#include <hip/hip_runtime.h>
#include <stdint.h>

// Farthest point sampling: b=16, n=65536, npoints=2048. Full-f64 decision
// pipeline (R5: harness ref is float64 ground-truth recompute; R5-R7 absmax 0).
//
// R8: attack the hidden cost found in R7's post-mortem — the poll was a
// maximally-scattered VMEM op (lane i -> slot i at 64-B stride = 64 lines
// PER LOAD x5 loads = ~320 transactions per retry).
//  - SoA slot layout: per (parity,batch) region = 4 arrays[64] of u64.
//    Poll load k touches arr_k[lane] -> 64 contiguous u64 = 8 lines. 4 loads
//    = 32 transactions (10x fewer).
//  - Slot payload shrunk 5->4 self-tagged words (bd 64b + idx 16b + xyz 96b
//    = 176b <= 4x48b):
//      w0=[bd_hi32|tag|idx] w1=[bd_lo32|tag|x_hi16]
//      w2=[y      |tag|x_lo16] w3=[z|tag|idx]
//  - Slim butterflies: shuffle only (bd, idx) (3 b32/stage vs 6), winner
//    lane/slot DERIVED from idx (lane = bi&63 within wave; slot =
//    ((wi>>12)<<2)|((wi>>6)&3) across waves — exact ownership inverses),
//    coords then fetched with 3 broadcast shuffles from that lane.
// Protocol unchanged (parity double-buffer, unique 16-bit tags, poison
// 0xAAAA unmatchable, skew <= 1 iteration by the rendezvous chain).

#define NBATCH   16
#define NPTS     65536
#define NPOINTS  2048
#define KBLK     16                  // blocks per batch
#define THREADS  256
#define WPB      64                  // waves per batch == wave width
#define PPB      4096                // points per block
#define PPT      16                  // points per thread
#define REGION_U64 (4 * WPB)         // 4 SoA arrays x 64 u64 = 2 KB / region

__global__ __launch_bounds__(THREADS, 1)
void fps_kernel(const float* __restrict__ pts, int* __restrict__ out,
                unsigned long long* __restrict__ slots)
{
    const int bid  = blockIdx.x;
    const int g    = bid & 15;       // batch (XCD co-location swizzle)
    const int blk  = bid >> 4;       // block within batch
    const int tid  = threadIdx.x;
    const int lane = tid & 63;
    const int wave = tid >> 6;
    const int widx = (blk << 2) + wave;   // wave index within batch, 0..63

    const float* __restrict__ P = pts + (size_t)g * (NPTS * 3);

    // Register-resident coords (f32; exact when widened to f64) + f64 dist.
    float  x[PPT], y[PPT], z[PPT];
    double dist[PPT];
    const int base = blk * PPB;
#pragma unroll
    for (int j = 0; j < PPT; ++j) {
        const int idx = base + j * THREADS + tid;
        x[j] = P[idx * 3 + 0];
        y[j] = P[idx * 3 + 1];
        z[j] = P[idx * 3 + 2];
        dist[j] = 1e10;              // never survives iteration 0
    }

    double qx = (double)P[0], qy = (double)P[1], qz = (double)P[2];
    if (blk == 0 && tid == 0) out[g * NPOINTS] = 0;

    for (int it = 0; it < NPOINTS - 1; ++it) {
        // ---- f64 min-dist update + thread-local argmax (first-max) ----
        double bd = -1.0;
        int    bi = 0x7FFFFFFF;
        float  lx = 0.f, ly = 0.f, lz = 0.f;   // this lane's candidate coords
        {
#pragma clang fp contract(off)
#pragma unroll
            for (int j = 0; j < PPT; ++j) {
                const double dx = (double)x[j] - qx;
                const double dy = (double)y[j] - qy;
                const double dz = (double)z[j] - qz;
                const double d  = (dx * dx + dy * dy) + dz * dz;
                const double nd = fmin(dist[j], d);
                dist[j] = nd;
                const bool t = nd > bd;          // strict: first-max kept
                bd = t ? nd : bd;
                bi = t ? (base + j * THREADS + tid) : bi;
                lx = t ? x[j] : lx;
                ly = t ? y[j] : ly;
                lz = t ? z[j] : lz;
            }
        }

        // ---- 64-lane butterfly argmax over (bd, bi) only ----
#pragma unroll
        for (int m = 1; m < 64; m <<= 1) {
            const double od = __shfl_xor(bd, m, 64);
            const int    oi = __shfl_xor(bi, m, 64);
            const bool t = (od > bd) || (od == bd && oi < bi);
            bd = t ? od : bd; bi = t ? oi : bi;
        }
        // winner lane within this wave is derivable: tid-part of bi, &63.
        const int lwin = bi & 63;
        const float wxf = __shfl(lx, lwin, 64);
        const float wyf = __shfl(ly, lwin, 64);
        const float wzf = __shfl(lz, lwin, 64);

        // ---- publish: lanes 0..3 store one self-tagged SoA word each ----
        const unsigned tag = (unsigned)(it + 1);
        const int par = it & 1;
        unsigned long long* rb =
            slots + (size_t)(par * NBATCH + g) * REGION_U64;

        {
            const unsigned long long B =
                (unsigned long long)__double_as_longlong(bd);
            const unsigned X = __float_as_uint(wxf);
            const unsigned Y = __float_as_uint(wyf);
            const unsigned Z = __float_as_uint(wzf);
            const unsigned I = (unsigned)bi & 0xFFFFu;

            const unsigned long long hi32 =
                  (lane == 0) ? (B >> 32)
                : (lane == 1) ? (B & 0xFFFFFFFFull)
                : (lane == 2) ? (unsigned long long)Y
                              : (unsigned long long)Z;
            const unsigned long long lo16 =
                  (lane == 0) ? (unsigned long long)I
                : (lane == 1) ? (unsigned long long)(X >> 16)
                : (lane == 2) ? (unsigned long long)(X & 0xFFFFu)
                              : (unsigned long long)I;
            if (lane < 4) {
                __hip_atomic_store(rb + lane * WPB + widx,
                                   (hi32 << 32)
                                 | ((unsigned long long)tag << 16) | lo16,
                                   __ATOMIC_RELAXED, __HIP_MEMORY_SCOPE_AGENT);
            }
        }

        // ---- poll: lane i watches slot i across the 4 SoA arrays ----
        unsigned long long l0, l1, l2, l3;
        int guard = 0;
        bool ok;
        do {
            l0 = __hip_atomic_load(rb + 0 * WPB + lane, __ATOMIC_RELAXED,
                                   __HIP_MEMORY_SCOPE_AGENT);
            l1 = __hip_atomic_load(rb + 1 * WPB + lane, __ATOMIC_RELAXED,
                                   __HIP_MEMORY_SCOPE_AGENT);
            l2 = __hip_atomic_load(rb + 2 * WPB + lane, __ATOMIC_RELAXED,
                                   __HIP_MEMORY_SCOPE_AGENT);
            l3 = __hip_atomic_load(rb + 3 * WPB + lane, __ATOMIC_RELAXED,
                                   __HIP_MEMORY_SCOPE_AGENT);
            ok = (((unsigned)(l0 >> 16) & 0xFFFFu) == tag)
               & (((unsigned)(l1 >> 16) & 0xFFFFu) == tag)
               & (((unsigned)(l2 >> 16) & 0xFFFFu) == tag)
               & (((unsigned)(l3 >> 16) & 0xFFFFu) == tag);
        } while (!ok && ++guard < (1 << 20));   // fail loud, never hang

        // reconstruct slot-lane's candidate
        double cd = __longlong_as_double(
            (long long)(((l0 >> 32) << 32) | (l1 >> 32)));
        int    ci = (int)(l0 & 0xFFFFull);
        const float cx = __uint_as_float(
            (unsigned)(((l1 & 0xFFFFull) << 16) | (l2 & 0xFFFFull)));
        const float cy = __uint_as_float((unsigned)(l2 >> 32));
        const float cz = __uint_as_float((unsigned)(l3 >> 32));

        // ---- 64-lane butterfly over (cd, ci) for the batch winner ----
#pragma unroll
        for (int m = 1; m < 64; m <<= 1) {
            const double od = __shfl_xor(cd, m, 64);
            const int    oi = __shfl_xor(ci, m, 64);
            const bool t = (od > cd) || (od == cd && oi < ci);
            cd = t ? od : cd; ci = t ? oi : ci;
        }
        // winner's owning slot derived from its global index:
        // blk = ci>>12 (4096 pts/block), wave = (ci>>6)&3 (tid = ci&255).
        const int ws = ((ci >> 12) << 2) | ((ci >> 6) & 3);
        const float px = __shfl(cx, ws, 64);
        const float py = __shfl(cy, ws, 64);
        const float pz = __shfl(cz, ws, 64);

        qx = (double)px; qy = (double)py; qz = (double)pz;

        if (widx == 0 && lane == 0) out[g * NPOINTS + it + 1] = ci;
    }
}

extern "C" void kernel_launch(void* const* d_in, const int* in_sizes, int n_in,
                              void* d_out, int out_size, void* d_ws, size_t ws_size,
                              hipStream_t stream) {
    (void)in_sizes; (void)n_in; (void)out_size; (void)ws_size;
    // d_in[0] = npoints (scalar, fixed 2048 per setup), d_in[1] = t_in
    const float* t_in = (const float*)d_in[1];
    int* out = (int*)d_out;
    unsigned long long* slots = (unsigned long long*)d_ws;  // 64 KB used

    dim3 grid(NBATCH * KBLK);
    dim3 block(THREADS);
    void* args[] = { (void*)&t_in, (void*)&out, (void*)&slots };
    hipLaunchCooperativeKernel((const void*)fps_kernel, grid, block, args, 0, stream);
}